// Round 5
// baseline (92.656 us; speedup 1.0000x reference)
//
#include <hip/hip_runtime.h>

// GHM-C loss, one-pass, register-only, software-pipelined:
//   q = (c==t) ? -p : p ; e = exp(-|q|) ; bce = max(q,0) + ln(1+e)
//   cthr = #{|q| < ln9, ln4, ln(7/3), ln(3/2)} (monotone) ; bin = q>=0 ? 9-cthr : cthr
//   Prefix sums (hi,lo) pairs in float2 (v_pk_add_f32); counts as packed 6-bit
//   words (aAll/aHi), lo = all - hi at flush. S[bin]/cnt[bin] reconstructed by
//   differencing in ghm_final.

#define NROWS 4194304
#define BINS 10

constexpr int BLOCK = 256;
constexpr int GRID  = 2048;
constexpr int STRD  = GRID * BLOCK; // 524288 ; rows/thread = 8 exactly

typedef float f2 __attribute__((ext_vector_type(2)));

__device__ __forceinline__ void elem8(
    const float4 a, const float4 b, const int t, const float w,
    f2& sp0, f2& sp1, f2& sp2, f2& sp3, f2& sp4,
    unsigned& aAll, unsigned& aHi)
{
    constexpr float NLOG2E = -1.4426950408889634f; // -log2(e)
    constexpr float LN2    = 0.6931471805599453f;
    constexpr float T0 = 2.1972245773362196f;  // ln 9
    constexpr float T1 = 1.3862943611198906f;  // ln 4
    constexpr float T2 = 0.8472978603872037f;  // ln(7/3)
    constexpr float T3 = 0.4054651081081644f;  // ln(3/2)
    const float wln2 = w * LN2;
    const float pv[8] = {a.x, a.y, a.z, a.w, b.x, b.y, b.z, b.w};
#pragma unroll
    for (int c = 0; c < 8; ++c) {
        const float p = pv[c];
        const float q = (c == t) ? -p : p;
        const float aq = __builtin_fabsf(q);                 // folds as modifier
        const float e = __builtin_amdgcn_exp2f(aq * NLOG2E); // exp(-|q|)
        const bool b0 = aq < T0, b1 = aq < T1, b2 = aq < T2, b3 = aq < T3;
        const bool qp = q >= 0.f;
        const float l = __builtin_amdgcn_logf(1.0f + e);     // log2(1+e)
        const float v = fmaf(l, wln2, w * fmaxf(q, 0.f));    // w * softplus(q)
        f2 vp; vp.x = qp ? v : 0.f; vp.y = v - vp.x;
        sp0 += vp;
        f2 g;
        g.x = b0 ? vp.x : 0.f; g.y = b0 ? vp.y : 0.f; sp1 += g;
        g.x = b1 ? vp.x : 0.f; g.y = b1 ? vp.y : 0.f; sp2 += g;
        g.x = b2 ? vp.x : 0.f; g.y = b2 ? vp.y : 0.f; sp3 += g;
        g.x = b3 ? vp.x : 0.f; g.y = b3 ? vp.y : 0.f; sp4 += g;
        unsigned lut = b0 ? 0x41u : 0x1u;  // sum_{j<=cthr} 64^j
        lut = b1 ? 0x1041u : lut;
        lut = b2 ? 0x41041u : lut;
        lut = b3 ? 0x1041041u : lut;
        aAll += lut;
        aHi  += qp ? lut : 0u;
    }
}

__device__ __forceinline__ void block_reduce_store(
    f2 sp0, f2 sp1, f2 sp2, f2 sp3, f2 sp4,
    const unsigned* cA, const unsigned* cH, float sumw,
    float* __restrict__ ws, int tid)
{
    float r21[21];
    r21[0] = sp0.x; r21[1] = sp1.x; r21[2] = sp2.x; r21[3] = sp3.x; r21[4] = sp4.x;
    r21[5] = sp0.y; r21[6] = sp1.y; r21[7] = sp2.y; r21[8] = sp3.y; r21[9] = sp4.y;
#pragma unroll
    for (int k = 0; k < 5; ++k) {
        r21[10 + k] = (float)cH[k];
        r21[15 + k] = (float)(cA[k] - cH[k]);
    }
    r21[20] = sumw;

#pragma unroll
    for (int i = 0; i < 21; ++i) {
        float x = r21[i];
#pragma unroll
        for (int o = 32; o >= 1; o >>= 1) x += __shfl_xor(x, o, 64);
        r21[i] = x;
    }

    __shared__ float red4[4][21];
    const int lane = tid & 63, wv = tid >> 6;
    if (lane == 0) {
#pragma unroll
        for (int i = 0; i < 21; ++i) red4[wv][i] = r21[i];
    }
    __syncthreads();
    if (tid < 21) {
        const float s = red4[0][tid] + red4[1][tid] + red4[2][tid] + red4[3][tid];
        // ws layout: [0..4]=PhiPre [5..9]=PloPre [10]=sumw [16..20]=CntHiPre [21..25]=CntLoPre
        const int slot = tid < 10 ? tid : (tid < 20 ? tid + 6 : 10);
        ws[blockIdx.x * 32 + slot] = s;
    }
}

__global__ __launch_bounds__(BLOCK, 3) void ghm_main_s(
    const float* __restrict__ pred, const int* __restrict__ target,
    const float* __restrict__ weight, float* __restrict__ ws)
{
    __shared__ float wlds[8];
    const int tid = threadIdx.x;
    if (tid < 8) wlds[tid] = weight[tid];
    __syncthreads();

    const int r0 = blockIdx.x * BLOCK + tid;
    const float4* __restrict__ p4 = reinterpret_cast<const float4*>(pred);

    int tt[8];
#pragma unroll
    for (int i = 0; i < 8; ++i) tt[i] = target[r0 + i * STRD];

    // group-0 pred loads
    float4 c0a = p4[2 * (size_t)(r0 + 0 * STRD)], c0b = p4[2 * (size_t)(r0 + 0 * STRD) + 1];
    float4 c1a = p4[2 * (size_t)(r0 + 1 * STRD)], c1b = p4[2 * (size_t)(r0 + 1 * STRD) + 1];
    float4 c2a = p4[2 * (size_t)(r0 + 2 * STRD)], c2b = p4[2 * (size_t)(r0 + 2 * STRD) + 1];
    float4 c3a = p4[2 * (size_t)(r0 + 3 * STRD)], c3b = p4[2 * (size_t)(r0 + 3 * STRD) + 1];

    float wr[8];
#pragma unroll
    for (int i = 0; i < 8; ++i) wr[i] = wlds[tt[i]];

    // group-1 pred loads (in flight while group-0 computes)
    float4 n0a = p4[2 * (size_t)(r0 + 4 * STRD)], n0b = p4[2 * (size_t)(r0 + 4 * STRD) + 1];
    float4 n1a = p4[2 * (size_t)(r0 + 5 * STRD)], n1b = p4[2 * (size_t)(r0 + 5 * STRD) + 1];
    float4 n2a = p4[2 * (size_t)(r0 + 6 * STRD)], n2b = p4[2 * (size_t)(r0 + 6 * STRD) + 1];
    float4 n3a = p4[2 * (size_t)(r0 + 7 * STRD)], n3b = p4[2 * (size_t)(r0 + 7 * STRD) + 1];

    f2 sp0 = {0, 0}, sp1 = {0, 0}, sp2 = {0, 0}, sp3 = {0, 0}, sp4 = {0, 0};
    unsigned cA[5] = {0, 0, 0, 0, 0}, cH[5] = {0, 0, 0, 0, 0};
    unsigned aAll = 0u, aHi = 0u;
    const float sumw = ((wr[0] + wr[1]) + (wr[2] + wr[3])) +
                       ((wr[4] + wr[5]) + (wr[6] + wr[7]));

    elem8(c0a, c0b, tt[0], wr[0], sp0, sp1, sp2, sp3, sp4, aAll, aHi);
    elem8(c1a, c1b, tt[1], wr[1], sp0, sp1, sp2, sp3, sp4, aAll, aHi);
    elem8(c2a, c2b, tt[2], wr[2], sp0, sp1, sp2, sp3, sp4, aAll, aHi);
    elem8(c3a, c3b, tt[3], wr[3], sp0, sp1, sp2, sp3, sp4, aAll, aHi);
#pragma unroll
    for (int k = 0; k < 5; ++k) { // 32 elems <= 63/field
        cA[k] += (aAll >> (6 * k)) & 63u;
        cH[k] += (aHi  >> (6 * k)) & 63u;
    }
    aAll = 0u; aHi = 0u;

    elem8(n0a, n0b, tt[4], wr[4], sp0, sp1, sp2, sp3, sp4, aAll, aHi);
    elem8(n1a, n1b, tt[5], wr[5], sp0, sp1, sp2, sp3, sp4, aAll, aHi);
    elem8(n2a, n2b, tt[6], wr[6], sp0, sp1, sp2, sp3, sp4, aAll, aHi);
    elem8(n3a, n3b, tt[7], wr[7], sp0, sp1, sp2, sp3, sp4, aAll, aHi);
#pragma unroll
    for (int k = 0; k < 5; ++k) {
        cA[k] += (aAll >> (6 * k)) & 63u;
        cH[k] += (aHi  >> (6 * k)) & 63u;
    }

    block_reduce_store(sp0, sp1, sp2, sp3, sp4, cA, cH, sumw, ws, tid);
}

// fallback for unexpected small ws_size (any grid)
__global__ __launch_bounds__(BLOCK) void ghm_main_d(
    const float* __restrict__ pred, const int* __restrict__ target,
    const float* __restrict__ weight, float* __restrict__ ws)
{
    __shared__ float wlds[8];
    const int tid = threadIdx.x;
    if (tid < 8) wlds[tid] = weight[tid];
    __syncthreads();

    f2 sp0 = {0, 0}, sp1 = {0, 0}, sp2 = {0, 0}, sp3 = {0, 0}, sp4 = {0, 0};
    unsigned cA[5] = {0, 0, 0, 0, 0}, cH[5] = {0, 0, 0, 0, 0};
    float sumw = 0.f;
    const int stride = gridDim.x * BLOCK;
    const float4* __restrict__ p4 = reinterpret_cast<const float4*>(pred);

    for (int r = blockIdx.x * BLOCK + tid; r < NROWS; r += stride) {
        const float4 a = p4[2 * (size_t)r], b = p4[2 * (size_t)r + 1];
        const int t = target[r];
        const float w = wlds[t];
        sumw += w;
        unsigned aAll = 0u, aHi = 0u;
        elem8(a, b, t, w, sp0, sp1, sp2, sp3, sp4, aAll, aHi);
#pragma unroll
        for (int k = 0; k < 5; ++k) {
            cA[k] += (aAll >> (6 * k)) & 63u;
            cH[k] += (aHi  >> (6 * k)) & 63u;
        }
    }
    block_reduce_store(sp0, sp1, sp2, sp3, sp4, cA, cH, sumw, ws, tid);
}

__global__ __launch_bounds__(BLOCK) void ghm_final(
    const float* __restrict__ ws, float* __restrict__ out, int nblocks)
{
    float a21[21];
#pragma unroll
    for (int i = 0; i < 21; ++i) a21[i] = 0.f;

    for (int b = threadIdx.x; b < nblocks; b += BLOCK) {
#pragma unroll
        for (int i = 0; i < 10; ++i) a21[i] += ws[b * 32 + i];
#pragma unroll
        for (int i = 0; i < 10; ++i) a21[10 + i] += ws[b * 32 + 16 + i];
        a21[20] += ws[b * 32 + 10];
    }

#pragma unroll
    for (int i = 0; i < 21; ++i) {
        float x = a21[i];
#pragma unroll
        for (int o = 32; o >= 1; o >>= 1) x += __shfl_xor(x, o, 64);
        a21[i] = x;
    }

    __shared__ float red[4][21];
    const int tid = threadIdx.x;
    const int lane = tid & 63, wv = tid >> 6;
    if (lane == 0) {
#pragma unroll
        for (int i = 0; i < 21; ++i) red[wv][i] = a21[i];
    }
    __syncthreads();
    if (tid == 0) {
        float T[21];
#pragma unroll
        for (int i = 0; i < 21; ++i)
            T[i] = red[0][i] + red[1][i] + red[2][i] + red[3][i];
        // T[0..4]=PhiPre T[5..9]=PloPre T[10..14]=CntHiPre T[15..19]=CntLoPre T[20]=sumw
        float S[10], CN[10];
#pragma unroll
        for (int k = 0; k < 5; ++k) {
            const float shn = (k < 4) ? T[k + 1]      : 0.f;
            const float sln = (k < 4) ? T[5 + k + 1]  : 0.f;
            const float chn = (k < 4) ? T[10 + k + 1] : 0.f;
            const float cln = (k < 4) ? T[15 + k + 1] : 0.f;
            S[9 - k] = T[k]     - shn;  CN[9 - k] = T[10 + k] - chn;
            S[k]     = T[5 + k] - sln;  CN[k]     = T[15 + k] - cln;
        }
        int nne = 0; float acc = 0.f;
        const float tot = 33554432.0f; // N*C
#pragma unroll
        for (int i = 0; i < 10; ++i) {
            if (CN[i] > 0.5f) { nne++; acc += S[i] * (tot / CN[i]); }
        }
        out[0] = acc / (float)nne / (8.0f * T[20]);
    }
}

extern "C" void kernel_launch(void* const* d_in, const int* in_sizes, int n_in,
                              void* d_out, int out_size, void* d_ws, size_t ws_size,
                              hipStream_t stream) {
    const float* pred   = (const float*)d_in[0];
    const int*   target = (const int*)d_in[1];
    const float* weight = (const float*)d_in[2];
    float* out = (float*)d_out;

    int blocks;
    if (ws_size >= (size_t)GRID * 128u) {
        blocks = GRID;
        ghm_main_s<<<GRID, BLOCK, 0, stream>>>(pred, target, weight, (float*)d_ws);
    } else {
        const int cap = (int)(ws_size / 128u);
        blocks = 1;
        while (blocks * 2 <= cap && blocks * 2 < GRID) blocks *= 2;
        ghm_main_d<<<blocks, BLOCK, 0, stream>>>(pred, target, weight, (float*)d_ws);
    }
    ghm_final<<<1, BLOCK, 0, stream>>>((const float*)d_ws, out, blocks);
}

// Round 6
// 54.475 us; speedup vs baseline: 1.7009x; 1.7009x over previous
//
#include <hip/hip_runtime.h>

// GHM-C loss, one-pass, register-only (R4 structure + SALU-pipe counts):
//   q = (c==t) ? -p : p ; e = exp(-|q|) ; bce = max(q,0) + ln(1+e)
//   cthr = #{|q| < ln9, ln4, ln(7/3), ln(3/2)} (monotone) ; bin = q>=0 ? 9-cthr : cthr
//   Values: prefix sums (hi,lo) as f2 pairs (VALU). Counts: ballot+popc on the
//   scalar pipe (wave-uniform, free under VALU). S[bin]/cnt[bin] reconstructed
//   by differencing in ghm_final.

#define NROWS 4194304

constexpr int BLOCK = 256;
constexpr int MAXGRID = 2048;

typedef float f2 __attribute__((ext_vector_type(2)));

__device__ __forceinline__ void elem8(
    const float4 a, const float4 b, const int t, const float w,
    f2& sp0, f2& sp1, f2& sp2, f2& sp3, f2& sp4,
    unsigned (&cA)[5], unsigned (&cH)[5])
{
    constexpr float NLOG2E = -1.4426950408889634f; // -log2(e)
    constexpr float LN2    = 0.6931471805599453f;
    constexpr float T0 = 2.1972245773362196f;  // ln 9
    constexpr float T1 = 1.3862943611198906f;  // ln 4
    constexpr float T2 = 0.8472978603872037f;  // ln(7/3)
    constexpr float T3 = 0.4054651081081644f;  // ln(3/2)
    const float wln2 = w * LN2;
    const float pv[8] = {a.x, a.y, a.z, a.w, b.x, b.y, b.z, b.w};
#pragma unroll
    for (int c = 0; c < 8; ++c) {
        const float p = pv[c];
        const float q = (c == t) ? -p : p;
        const float aq = __builtin_fabsf(q);                 // folds as modifier
        const float e = __builtin_amdgcn_exp2f(aq * NLOG2E); // exp(-|q|)
        const bool b0 = aq < T0, b1 = aq < T1, b2 = aq < T2, b3 = aq < T3;
        const bool qp = q >= 0.f;
        const float l = __builtin_amdgcn_logf(1.0f + e);     // log2(1+e)
        const float v = fmaf(l, wln2, w * fmaxf(q, 0.f));    // w * softplus(q)
        f2 vp; vp.x = qp ? v : 0.f; vp.y = v - vp.x;
        sp0 += vp;
        f2 g;
        g.x = b0 ? vp.x : 0.f; g.y = b0 ? vp.y : 0.f; sp1 += g;
        g.x = b1 ? vp.x : 0.f; g.y = b1 ? vp.y : 0.f; sp2 += g;
        g.x = b2 ? vp.x : 0.f; g.y = b2 ? vp.y : 0.f; sp3 += g;
        g.x = b3 ? vp.x : 0.f; g.y = b3 ? vp.y : 0.f; sp4 += g;
        // counts: scalar pipe (s_and/s_bcnt1/s_add), overlaps the VALU work.
        // full wave always active (grids divide NROWS exactly).
        cA[0] += 64u;
        cH[0] += (unsigned)__popcll(__ballot(qp));
        cA[1] += (unsigned)__popcll(__ballot(b0));
        cH[1] += (unsigned)__popcll(__ballot(qp && b0));
        cA[2] += (unsigned)__popcll(__ballot(b1));
        cH[2] += (unsigned)__popcll(__ballot(qp && b1));
        cA[3] += (unsigned)__popcll(__ballot(b2));
        cH[3] += (unsigned)__popcll(__ballot(qp && b2));
        cA[4] += (unsigned)__popcll(__ballot(b3));
        cH[4] += (unsigned)__popcll(__ballot(qp && b3));
    }
}

__device__ __forceinline__ void block_reduce_store(
    f2 sp0, f2 sp1, f2 sp2, f2 sp3, f2 sp4,
    const unsigned (&cA)[5], const unsigned (&cH)[5], float sumw,
    float* __restrict__ ws, int tid)
{
    float r11[11];
    r11[0] = sp0.x; r11[1] = sp1.x; r11[2] = sp2.x; r11[3] = sp3.x; r11[4] = sp4.x;
    r11[5] = sp0.y; r11[6] = sp1.y; r11[7] = sp2.y; r11[8] = sp3.y; r11[9] = sp4.y;
    r11[10] = sumw;

#pragma unroll
    for (int i = 0; i < 11; ++i) {
        float x = r11[i];
#pragma unroll
        for (int o = 32; o >= 1; o >>= 1) x += __shfl_xor(x, o, 64);
        r11[i] = x;
    }

    __shared__ float red4[4][21];
    const int lane = tid & 63, wv = tid >> 6;
    if (lane == 0) {
#pragma unroll
        for (int i = 0; i < 11; ++i) red4[wv][i] = r11[i];
#pragma unroll
        for (int k = 0; k < 5; ++k) {
            red4[wv][11 + k] = (float)cH[k];          // CntHiPre (wave-uniform)
            red4[wv][16 + k] = (float)(cA[k] - cH[k]); // CntLoPre
        }
    }
    __syncthreads();
    if (tid < 21) {
        const float s = red4[0][tid] + red4[1][tid] + red4[2][tid] + red4[3][tid];
        // ws layout: [0..4]=PhiPre [5..9]=PloPre [10]=sumw [16..20]=CntHiPre [21..25]=CntLoPre
        const int slot = tid < 11 ? tid : tid + 5;
        ws[blockIdx.x * 32 + slot] = s;
    }
}

__global__ __launch_bounds__(BLOCK) void ghm_main(
    const float* __restrict__ pred, const int* __restrict__ target,
    const float* __restrict__ weight, float* __restrict__ ws)
{
    __shared__ float wlds[8];
    const int tid = threadIdx.x;
    if (tid < 8) wlds[tid] = weight[tid];
    __syncthreads();

    f2 sp0 = {0, 0}, sp1 = {0, 0}, sp2 = {0, 0}, sp3 = {0, 0}, sp4 = {0, 0};
    unsigned cA[5] = {0, 0, 0, 0, 0}, cH[5] = {0, 0, 0, 0, 0};
    float sumw = 0.f;
    const int stride = gridDim.x * BLOCK;
    const float4* __restrict__ p4 = reinterpret_cast<const float4*>(pred);

    // pow2 grids <= 4096 divide NROWS by 4*stride exactly -> no inner bounds check
    for (int r = blockIdx.x * BLOCK + tid; r < NROWS; ) {
#pragma unroll
        for (int k = 0; k < 4; ++k, r += stride) {
            const float4 a = p4[2 * (size_t)r], b = p4[2 * (size_t)r + 1];
            const int t = target[r];
            const float w = wlds[t];
            sumw += w;
            elem8(a, b, t, w, sp0, sp1, sp2, sp3, sp4, cA, cH);
        }
    }
    block_reduce_store(sp0, sp1, sp2, sp3, sp4, cA, cH, sumw, ws, tid);
}

__global__ __launch_bounds__(BLOCK) void ghm_final(
    const float* __restrict__ ws, float* __restrict__ out, int nblocks)
{
    float a21[21];
#pragma unroll
    for (int i = 0; i < 21; ++i) a21[i] = 0.f;

    for (int b = threadIdx.x; b < nblocks; b += BLOCK) {
#pragma unroll
        for (int i = 0; i < 10; ++i) a21[i] += ws[b * 32 + i];
#pragma unroll
        for (int i = 0; i < 10; ++i) a21[10 + i] += ws[b * 32 + 16 + i];
        a21[20] += ws[b * 32 + 10];
    }

#pragma unroll
    for (int i = 0; i < 21; ++i) {
        float x = a21[i];
#pragma unroll
        for (int o = 32; o >= 1; o >>= 1) x += __shfl_xor(x, o, 64);
        a21[i] = x;
    }

    __shared__ float red[4][21];
    const int tid = threadIdx.x;
    const int lane = tid & 63, wv = tid >> 6;
    if (lane == 0) {
#pragma unroll
        for (int i = 0; i < 21; ++i) red[wv][i] = a21[i];
    }
    __syncthreads();
    if (tid == 0) {
        float T[21];
#pragma unroll
        for (int i = 0; i < 21; ++i)
            T[i] = red[0][i] + red[1][i] + red[2][i] + red[3][i];
        // T[0..4]=PhiPre T[5..9]=PloPre T[10..14]=CntHiPre T[15..19]=CntLoPre T[20]=sumw
        float S[10], CN[10];
#pragma unroll
        for (int k = 0; k < 5; ++k) {
            const float shn = (k < 4) ? T[k + 1]      : 0.f;
            const float sln = (k < 4) ? T[5 + k + 1]  : 0.f;
            const float chn = (k < 4) ? T[10 + k + 1] : 0.f;
            const float cln = (k < 4) ? T[15 + k + 1] : 0.f;
            S[9 - k] = T[k]     - shn;  CN[9 - k] = T[10 + k] - chn;
            S[k]     = T[5 + k] - sln;  CN[k]     = T[15 + k] - cln;
        }
        int nne = 0; float acc = 0.f;
        const float tot = 33554432.0f; // N*C
#pragma unroll
        for (int i = 0; i < 10; ++i) {
            if (CN[i] > 0.5f) { nne++; acc += S[i] * (tot / CN[i]); }
        }
        out[0] = acc / (float)nne / (8.0f * T[20]);
    }
}

extern "C" void kernel_launch(void* const* d_in, const int* in_sizes, int n_in,
                              void* d_out, int out_size, void* d_ws, size_t ws_size,
                              hipStream_t stream) {
    const float* pred   = (const float*)d_in[0];
    const int*   target = (const int*)d_in[1];
    const float* weight = (const float*)d_in[2];
    float* out = (float*)d_out;

    int blocks = MAXGRID;
    if (ws_size < (size_t)MAXGRID * 128u) {
        const int cap = (int)(ws_size / 128u);
        blocks = 1;
        while (blocks * 2 <= cap && blocks * 2 < MAXGRID) blocks *= 2; // pow2: exact divisibility
    }

    ghm_main<<<blocks, BLOCK, 0, stream>>>(pred, target, weight, (float*)d_ws);
    ghm_final<<<1, BLOCK, 0, stream>>>((const float*)d_ws, out, blocks);
}

// Round 7
// 48.011 us; speedup vs baseline: 1.9299x; 1.1346x over previous
//
#include <hip/hip_runtime.h>

// GHM-C loss, one-pass, register-only (R6 structure, flattened codegen):
//   q = (c==t) ? -p : p ; e = exp(-|q|) ; bce = max(q,0) + ln(1+e)
//   cthr = #{|q| < ln9, ln4, ln(7/3), ln(3/2)} (monotone) ; bin = q>=0 ? 9-cthr : cthr
//   A_i = sum of v gated by b_i ; B_i = sum of (qp ? v : -v) gated by b_i
//   -> PhiPre_i = (A_i+B_i)/2, PloPre_i = (A_i-B_i)/2 (converted once at end).
//   Counts: ballot-mask algebra, popc on SALU. S[bin]/cnt[bin] by differencing
//   in ghm_final (unchanged from R6).

#define NROWS 4194304

constexpr int BLOCK = 256;
constexpr int MAXGRID = 2048;

__global__ __launch_bounds__(BLOCK) void ghm_main(
    const float* __restrict__ pred, const int* __restrict__ target,
    const float* __restrict__ weight, float* __restrict__ ws)
{
    __shared__ float wlds[8];
    const int tid = threadIdx.x;
    if (tid < 8) wlds[tid] = weight[tid];
    __syncthreads();

    float A0 = 0.f, A1 = 0.f, A2 = 0.f, A3 = 0.f, A4 = 0.f;
    float B0 = 0.f, B1 = 0.f, B2 = 0.f, B3 = 0.f, B4 = 0.f;
    unsigned cH0 = 0u, cH1 = 0u, cH2 = 0u, cH3 = 0u, cH4 = 0u;
    unsigned cA1 = 0u, cA2 = 0u, cA3 = 0u, cA4 = 0u;
    unsigned nrows = 0u;
    float sumw = 0.f;

    const int stride = gridDim.x * BLOCK;
    const float4* __restrict__ p4 = reinterpret_cast<const float4*>(pred);

    constexpr float NLOG2E = -1.4426950408889634f; // -log2(e)
    constexpr float LN2    = 0.6931471805599453f;
    constexpr float T0 = 2.1972245773362196f;  // ln 9
    constexpr float T1 = 1.3862943611198906f;  // ln 4
    constexpr float T2 = 0.8472978603872037f;  // ln(7/3)
    constexpr float T3 = 0.4054651081081644f;  // ln(3/2)

    for (int r = blockIdx.x * BLOCK + tid; r < NROWS; r += stride) {
        const float4 a = p4[2 * (size_t)r];
        const float4 b = p4[2 * (size_t)r + 1];
        const int t = target[r];
        const float w = wlds[t];
        sumw += w;
        ++nrows;
        const float wln2 = w * LN2;

#define GHM_ELEM(P, CI) { \
        const float q  = ((CI) == t) ? -(P) : (P); \
        const float aq = __builtin_fabsf(q); \
        const float e  = __builtin_amdgcn_exp2f(aq * NLOG2E); \
        const float l  = __builtin_amdgcn_logf(1.0f + e); \
        const float v  = fmaf(l, wln2, w * fmaxf(q, 0.0f)); \
        const bool qp = q >= 0.0f; \
        const bool b0 = aq < T0; \
        const bool b1 = aq < T1; \
        const bool b2 = aq < T2; \
        const bool b3 = aq < T3; \
        const float sv = qp ? v : -v; \
        const float m0 = b0 ? 1.0f : 0.0f; \
        const float m1 = b1 ? 1.0f : 0.0f; \
        const float m2 = b2 ? 1.0f : 0.0f; \
        const float m3 = b3 ? 1.0f : 0.0f; \
        A0 += v;  B0 += sv; \
        A1 = fmaf(v, m0, A1);  B1 = fmaf(sv, m0, B1); \
        A2 = fmaf(v, m1, A2);  B2 = fmaf(sv, m1, B2); \
        A3 = fmaf(v, m2, A3);  B3 = fmaf(sv, m2, B3); \
        A4 = fmaf(v, m3, A4);  B4 = fmaf(sv, m3, B4); \
        const unsigned long long Mq = __ballot(qp); \
        const unsigned long long M0 = __ballot(b0); \
        const unsigned long long M1 = __ballot(b1); \
        const unsigned long long M2 = __ballot(b2); \
        const unsigned long long M3 = __ballot(b3); \
        cH0 += (unsigned)__popcll(Mq); \
        cA1 += (unsigned)__popcll(M0);  cH1 += (unsigned)__popcll(Mq & M0); \
        cA2 += (unsigned)__popcll(M1);  cH2 += (unsigned)__popcll(Mq & M1); \
        cA3 += (unsigned)__popcll(M2);  cH3 += (unsigned)__popcll(Mq & M2); \
        cA4 += (unsigned)__popcll(M3);  cH4 += (unsigned)__popcll(Mq & M3); \
    }
        GHM_ELEM(a.x, 0) GHM_ELEM(a.y, 1) GHM_ELEM(a.z, 2) GHM_ELEM(a.w, 3)
        GHM_ELEM(b.x, 4) GHM_ELEM(b.y, 5) GHM_ELEM(b.z, 6) GHM_ELEM(b.w, 7)
#undef GHM_ELEM
    }

    // convert (A,B) -> (PhiPre, PloPre); counts are wave-uniform scalars
    float r11[11];
    r11[0] = 0.5f * (A0 + B0); r11[5] = 0.5f * (A0 - B0);
    r11[1] = 0.5f * (A1 + B1); r11[6] = 0.5f * (A1 - B1);
    r11[2] = 0.5f * (A2 + B2); r11[7] = 0.5f * (A2 - B2);
    r11[3] = 0.5f * (A3 + B3); r11[8] = 0.5f * (A3 - B3);
    r11[4] = 0.5f * (A4 + B4); r11[9] = 0.5f * (A4 - B4);
    r11[10] = sumw;

#pragma unroll
    for (int i = 0; i < 11; ++i) {
        float x = r11[i];
#pragma unroll
        for (int o = 32; o >= 1; o >>= 1) x += __shfl_xor(x, o, 64);
        r11[i] = x;
    }

    const unsigned cA0 = nrows * 512u; // 8 elems * 64 lanes per row, full waves
    __shared__ float red4[4][21];
    const int lane = tid & 63, wv = tid >> 6;
    if (lane == 0) {
#pragma unroll
        for (int i = 0; i < 11; ++i) red4[wv][i] = r11[i];
        red4[wv][11] = (float)cH0;         red4[wv][16] = (float)(cA0 - cH0);
        red4[wv][12] = (float)cH1;         red4[wv][17] = (float)(cA1 - cH1);
        red4[wv][13] = (float)cH2;         red4[wv][18] = (float)(cA2 - cH2);
        red4[wv][14] = (float)cH3;         red4[wv][19] = (float)(cA3 - cH3);
        red4[wv][15] = (float)cH4;         red4[wv][20] = (float)(cA4 - cH4);
    }
    __syncthreads();
    if (tid < 21) {
        const float s = red4[0][tid] + red4[1][tid] + red4[2][tid] + red4[3][tid];
        // ws layout: [0..4]=PhiPre [5..9]=PloPre [10]=sumw [16..20]=CntHiPre [21..25]=CntLoPre
        const int slot = tid < 11 ? tid : tid + 5;
        ws[blockIdx.x * 32 + slot] = s;
    }
}

__global__ __launch_bounds__(BLOCK) void ghm_final(
    const float* __restrict__ ws, float* __restrict__ out, int nblocks)
{
    float a21[21];
#pragma unroll
    for (int i = 0; i < 21; ++i) a21[i] = 0.f;

    for (int b = threadIdx.x; b < nblocks; b += BLOCK) {
#pragma unroll
        for (int i = 0; i < 10; ++i) a21[i] += ws[b * 32 + i];
#pragma unroll
        for (int i = 0; i < 10; ++i) a21[10 + i] += ws[b * 32 + 16 + i];
        a21[20] += ws[b * 32 + 10];
    }

#pragma unroll
    for (int i = 0; i < 21; ++i) {
        float x = a21[i];
#pragma unroll
        for (int o = 32; o >= 1; o >>= 1) x += __shfl_xor(x, o, 64);
        a21[i] = x;
    }

    __shared__ float red[4][21];
    const int tid = threadIdx.x;
    const int lane = tid & 63, wv = tid >> 6;
    if (lane == 0) {
#pragma unroll
        for (int i = 0; i < 21; ++i) red[wv][i] = a21[i];
    }
    __syncthreads();
    if (tid == 0) {
        float T[21];
#pragma unroll
        for (int i = 0; i < 21; ++i)
            T[i] = red[0][i] + red[1][i] + red[2][i] + red[3][i];
        // T[0..4]=PhiPre T[5..9]=PloPre T[10..14]=CntHiPre T[15..19]=CntLoPre T[20]=sumw
        float S[10], CN[10];
#pragma unroll
        for (int k = 0; k < 5; ++k) {
            const float shn = (k < 4) ? T[k + 1]      : 0.f;
            const float sln = (k < 4) ? T[5 + k + 1]  : 0.f;
            const float chn = (k < 4) ? T[10 + k + 1] : 0.f;
            const float cln = (k < 4) ? T[15 + k + 1] : 0.f;
            S[9 - k] = T[k]     - shn;  CN[9 - k] = T[10 + k] - chn;
            S[k]     = T[5 + k] - sln;  CN[k]     = T[15 + k] - cln;
        }
        int nne = 0; float acc = 0.f;
        const float tot = 33554432.0f; // N*C
#pragma unroll
        for (int i = 0; i < 10; ++i) {
            if (CN[i] > 0.5f) { nne++; acc += S[i] * (tot / CN[i]); }
        }
        out[0] = acc / (float)nne / (8.0f * T[20]);
    }
}

extern "C" void kernel_launch(void* const* d_in, const int* in_sizes, int n_in,
                              void* d_out, int out_size, void* d_ws, size_t ws_size,
                              hipStream_t stream) {
    const float* pred   = (const float*)d_in[0];
    const int*   target = (const int*)d_in[1];
    const float* weight = (const float*)d_in[2];
    float* out = (float*)d_out;

    int blocks = MAXGRID;
    if (ws_size < (size_t)MAXGRID * 128u) {
        const int cap = (int)(ws_size / 128u);
        blocks = 1;
        while (blocks * 2 <= cap && blocks * 2 < MAXGRID) blocks *= 2; // pow2: exact divisibility
    }

    ghm_main<<<blocks, BLOCK, 0, stream>>>(pred, target, weight, (float*)d_ws);
    ghm_final<<<1, BLOCK, 0, stream>>>((const float*)d_ws, out, blocks);
}